// Round 8
// baseline (169.867 us; speedup 1.0000x reference)
//
#include <hip/hip_runtime.h>
#include <hip/hip_bf16.h>

#define H 16
#define D 64
#define NSEQ 4096
#define BM 256         // Q rows per block (4 q-groups x 64 rows)
#define BN 64          // keys per tile
#define NT (NSEQ / BN) // 64 tiles total
#define NTH (NT / 2)   // 32 tiles per key-half

typedef __attribute__((ext_vector_type(8))) short bf16x8;   // MFMA A/B frag (4 VGPRs)
typedef __attribute__((ext_vector_type(4))) short short4v;
typedef __attribute__((ext_vector_type(4))) float f32x4;    // MFMA C/D frag
typedef __attribute__((ext_vector_type(4))) float f4v;

union BF8 { bf16x8 v; unsigned u[4]; };
union S4  { short4v s; unsigned u[2]; };

// pack two fp32 -> one dword of bf16 (RNE), v_cvt_pk_bf16_f32 on gfx950
static __device__ __forceinline__ unsigned pk2(float lo, float hi) {
    __hip_bfloat162 h = __float22bfloat162_rn(float2{lo, hi});
    unsigned u;
    __builtin_memcpy(&u, &h, 4);
    return u;
}

static __device__ __forceinline__ float fexp2(float x) {
#if __has_builtin(__builtin_amdgcn_exp2f)
    return __builtin_amdgcn_exp2f(x);
#else
    return exp2f(x);
#endif
}

#define TO_GBL(p) ((const __attribute__((address_space(1))) int*)(unsigned long long)(p))
#define TO_LDS(p) ((__attribute__((address_space(3))) int*)(unsigned int)(unsigned long long)(p))

// ---- preprocess: K fp32 [n][h][d] -> bf16 [h][n][d];
//      V fp32 [n][h][d] -> bf16 V^T [h][d][n'] (sigma key-permutation per 32-group) ----
__global__ void prep(const float* __restrict__ k, const float* __restrict__ v,
                     short* __restrict__ kb, short* __restrict__ vt) {
    __shared__ short L[64 * 72];
    const int h = blockIdx.y, n0 = blockIdx.x * 64, t = threadIdx.x;
    const int rw = t >> 4, c4 = (t & 15) * 4;
    #pragma unroll
    for (int it = 0; it < 4; ++it) {
        const int row = rw + it * 16;
        const size_t gro = ((size_t)(n0 + row) * H + h) * D + c4;
        f4v kf = *(const f4v*)(k + gro);
        S4 ks;
        ks.u[0] = pk2(kf[0], kf[1]);
        ks.u[1] = pk2(kf[2], kf[3]);
        *(short4v*)(kb + ((size_t)h * NSEQ + n0 + row) * D + c4) = ks.s;

        f4v vf = *(const f4v*)(v + gro);
        S4 vs;
        vs.u[0] = pk2(vf[0], vf[1]);
        vs.u[1] = pk2(vf[2], vf[3]);
        *(short4v*)&L[row * 72 + c4] = vs.s;
    }
    __syncthreads();
    // 4x4 in-register transpose: thread t owns seq-slots r0..r0+3 x d0..d0+3
    const int tr = t & 15, tc = t >> 4;
    const int r0 = tr * 4, d0 = tc * 4;
    short4v ra[4];
    #pragma unroll
    for (int i = 0; i < 4; ++i) {
        const int s = r0 + i, s32 = s & 31, base32 = (s >> 5) * 32;
        const int phys = base32 + ((s32 >> 3) * 4 + (s32 & 3) + 16 * ((s32 >> 2) & 1));
        ra[i] = *(const short4v*)&L[phys * 72 + d0];
    }
    #pragma unroll
    for (int jj = 0; jj < 4; ++jj) {
        short4v o4 = (short4v){ra[0][jj], ra[1][jj], ra[2][jj], ra[3][jj]};
        *(short4v*)(vt + ((size_t)(h * D + d0 + jj)) * NSEQ + n0 + r0) = o4;
    }
}

// ---------------- main attention kernel ----------------
// R8 = R7 body with the REGISTER CEILING FIXED (one variable).
// R6/R7 post-mortem: __launch_bounds__(512, 2) follows CUDA semantics (min BLOCKS/CU)
// -> 16 waves/CU = 4 waves/SIMD -> VGPR cap 512/4 = 128 (both rounds reported exactly
// 128 + scratch traffic). But LDS (128 KB/block) limits us to 1 block/CU anyway, so
// the bound only throttled registers. Here: flat bound + amdgpu_waves_per_eu(2)
// -> VGPR cap 256, preserving the LDS-limited 2 waves/SIMD while letting the
// delayed-PV window's ~170-reg live set stay in registers. This is the repaired test
// of R7's interleave hypothesis:
//   qk(a); sm(a)->pbA; qk(b); { sm(b) interleaved with pv(a) }; pv(b)
// pv(a) depends only on pbA (32 VGPR carry), sm(b) only on st_b -> independent
// chains adjacent in one region. Spill tripwires: WRITE_SIZE must return to 16384 KB,
// FETCH to ~16.5 MB, VGPR_Count > 128.
__global__ __launch_bounds__(512)
__attribute__((amdgpu_waves_per_eu(2)))
void attn_fwd(const float* __restrict__ q, const short* __restrict__ kb,
              const short* __restrict__ vtb, float* __restrict__ out)
{
    // XCD swizzle (T1, verified FETCH 73.8->16.5 MB): 256 blocks, (lin&7)=XCD,
    // 2 heads per XCD -> 2 MB K/V working set <= 4 MB L2. Bijective: 256%8==0.
    const int lin   = blockIdx.x;
    const int idx   = lin >> 3;              // 0..31 within this XCD
    const int h     = (lin & 7) * 2 + (idx >> 4);
    const int qbase = (idx & 15) * BM;

    const int tid   = threadIdx.x;
    const int wave  = tid >> 6;              // 0..7
    const int kg    = wave >> 2;             // key-half: 0 -> tiles 0..31, 1 -> 32..63
    const int qg    = wave & 3;              // q-group / stager index within half
    const int lane  = tid & 63;
    const int lm    = lane & 15;
    const int quad  = lane >> 4;
    const int sw    = lm & 7;
    const int T0    = kg * NTH;              // tile offset of this key-half

    // per-key-half ring-4 buffers: 2 x (4x8KB K + 4x8KB V) = 128 KB
    __shared__ short Kt[2][4][BN * D];   // [kg][slot][key*64+d], 16B-chunk XOR-swizzled
    __shared__ short Vt[2][4][BN * D];   // [kg][slot][d*64+key'], sigma-permuted, XOR-swizzled

    const float c1 = 0.18033688011112042f;   // 0.125 * log2(e), folded into Q

    // Q fragments (B-operand of S^T mfma): B[n=lm][k = kc*32 + quad*8 + j], pre-scaled
    bf16x8 bq[4][2];
    #pragma unroll
    for (int g = 0; g < 4; ++g) {
        const int qrow = qbase + qg * 64 + g * 16 + lm;
        #pragma unroll
        for (int kc = 0; kc < 2; ++kc) {
            const float* qp = q + ((size_t)qrow * H + h) * D + kc * 32 + quad * 8;
            f4v q0 = *(const f4v*)qp;
            f4v q1 = *(const f4v*)(qp + 4);
            BF8 b;
            b.u[0] = pk2(q0[0] * c1, q0[1] * c1); b.u[1] = pk2(q0[2] * c1, q0[3] * c1);
            b.u[2] = pk2(q1[0] * c1, q1[1] * c1); b.u[3] = pk2(q1[2] * c1, q1[3] * c1);
            bq[g][kc] = b.v;
        }
    }

    // all-ones A fragment for the l-accumulating MFMA (bf16 1.0 = 0x3F80)
    BF8 ones;
    ones.u[0] = ones.u[1] = ones.u[2] = ones.u[3] = 0x3F803F80u;

    const f32x4 fz = (f32x4){0.f, 0.f, 0.f, 0.f};
    f32x4 o[4][4];   // O^T accum: lane holds d=mb*16+quad*4+r, q=g*16+lm
    #pragma unroll
    for (int g = 0; g < 4; ++g)
        #pragma unroll
        for (int mb = 0; mb < 4; ++mb) o[g][mb] = fz;
    f32x4 lacc[4];   // l accum via ones-MFMA: each lane's [r] = full partial l
    lacc[0] = fz; lacc[1] = fz; lacc[2] = fz; lacc[3] = fz;

    // staging (R2's verified pattern, stager = qg): 512 x 16B chunks per 8KB buffer;
    // chunk ci -> row ci>>3, pos ci&7, source column chunk = pos ^ (row&7)
    const int ci0 = (qg * 2 + 0) * 64 + lane;
    const int ci1 = (qg * 2 + 1) * 64 + lane;
    const int kr0 = ci0 >> 3, kp0 = (ci0 & 7) ^ (kr0 & 7);
    const int kr1 = ci1 >> 3, kp1 = (ci1 & 7) ^ (kr1 & 7);

    const short* kh = kb  + (size_t)h * NSEQ * D;
    const short* vh = vtb + (size_t)h * D * NSEQ;
    const short* pkA = kh + (size_t)(T0 * BN + kr0) * D + kp0 * 8;
    const short* pkB = kh + (size_t)(T0 * BN + kr1) * D + kp1 * 8;
    const short* pvA = vh + (size_t)kr0 * NSEQ + T0 * BN + kp0 * 8;
    const short* pvB = vh + (size_t)kr1 * NSEQ + T0 * BN + kp1 * 8;

    auto issue = [&](int b) {
        __builtin_amdgcn_global_load_lds(TO_GBL(pkA), TO_LDS(&Kt[kg][b][(qg * 2 + 0) * 512]), 16, 0, 0);
        __builtin_amdgcn_global_load_lds(TO_GBL(pkB), TO_LDS(&Kt[kg][b][(qg * 2 + 1) * 512]), 16, 0, 0);
        __builtin_amdgcn_global_load_lds(TO_GBL(pvA), TO_LDS(&Vt[kg][b][(qg * 2 + 0) * 512]), 16, 0, 0);
        __builtin_amdgcn_global_load_lds(TO_GBL(pvB), TO_LDS(&Vt[kg][b][(qg * 2 + 1) * 512]), 16, 0, 0);
        pkA += BN * D; pkB += BN * D; pvA += BN; pvB += BN;
    };

    const int posK0 = ((0 + quad) ^ sw) * 8;
    const int posK1 = ((4 + quad) ^ sw) * 8;

    // ---- pipeline stages ----
    // qk: 8 ds_read_b128 + 32 MFMA (K-frag reuse across 4 g's)
    auto qk = [&](int b, f32x4 (&st)[4][4]) {
        const short* K_ = Kt[kg][b];
        bf16x8 kf0[4], kf1[4];
        #pragma unroll
        for (int nb = 0; nb < 4; ++nb) {
            kf0[nb] = *(const bf16x8*)&K_[(nb * 16 + lm) * 64 + posK0];
            kf1[nb] = *(const bf16x8*)&K_[(nb * 16 + lm) * 64 + posK1];
        }
        #pragma unroll
        for (int g = 0; g < 4; ++g)
            #pragma unroll
            for (int nb = 0; nb < 4; ++nb) {
                st[g][nb] = __builtin_amdgcn_mfma_f32_16x16x32_bf16(kf0[nb], bq[g][0], fz, 0, 0, 0);
                st[g][nb] = __builtin_amdgcn_mfma_f32_16x16x32_bf16(kf1[nb], bq[g][1], st[g][nb], 0, 0, 0);
            }
    };

    // smg: exp+pack for ONE g (16 exp2 on trans + 8 cvt_pk on VALU)
    auto smg = [&](f32x4 (&st)[4][4], BF8 (&pb)[4][2], int g) {
        #pragma unroll
        for (int nb = 0; nb < 4; ++nb)
            #pragma unroll
            for (int r = 0; r < 4; ++r)
                st[g][nb][r] = fexp2(st[g][nb][r]);
        #pragma unroll
        for (int c = 0; c < 2; ++c) {
            pb[g][c].u[0] = pk2(st[g][2 * c][0],     st[g][2 * c][1]);
            pb[g][c].u[1] = pk2(st[g][2 * c][2],     st[g][2 * c][3]);
            pb[g][c].u[2] = pk2(st[g][2 * c + 1][0], st[g][2 * c + 1][1]);
            pb[g][c].u[3] = pk2(st[g][2 * c + 1][2], st[g][2 * c + 1][3]);
        }
    };

    // pvc: one c-half of PV: 4 l-acc MFMA + 4 ds_read_b128 + 16 PV MFMA
    auto pvc = [&](int b, BF8 (&pb)[4][2], int c) {
        const short* V_ = Vt[kg][b];
        #pragma unroll
        for (int g = 0; g < 4; ++g)
            lacc[g] = __builtin_amdgcn_mfma_f32_16x16x32_bf16(ones.v, pb[g][c].v, lacc[g], 0, 0, 0);
        const int pos = ((c * 4 + quad) ^ sw) * 8;
        #pragma unroll
        for (int mb = 0; mb < 4; ++mb) {
            bf16x8 vf = *(const bf16x8*)&V_[(mb * 16 + lm) * 64 + pos];
            #pragma unroll
            for (int g = 0; g < 4; ++g)
                o[g][mb] = __builtin_amdgcn_mfma_f32_16x16x32_bf16(vf, pb[g][c].v, o[g][mb], 0, 0, 0);
        }
    };

    // delayed-PV window: only cross-stage carry is pbA (32 VGPR). st is reused for
    // both tiles (SSA renaming, no forced serialization). sm(b) bursts sit between
    // pv(a) halves -> VALU work always has independent MFMA work adjacent.
    auto window = [&](int a, int b) {
        f32x4 st[4][4];
        BF8 pbA[4][2], pbB[4][2];
        qk(a, st);
        smg(st, pbA, 0); smg(st, pbA, 1); smg(st, pbA, 2); smg(st, pbA, 3);
        qk(b, st);
        smg(st, pbB, 0); smg(st, pbB, 1);
        pvc(a, pbA, 0);
        smg(st, pbB, 2); smg(st, pbB, 3);
        pvc(a, pbA, 1);
        pvc(b, pbB, 0);
        pvc(b, pbB, 1);
    };

    // ---- pair-window schedule (one barrier + one vmcnt(0) per two tiles), 32 tiles ----
#define WAITV0 asm volatile("s_waitcnt vmcnt(0)" ::: "memory")
#define BARRIER() do { __builtin_amdgcn_s_barrier(); asm volatile("" ::: "memory"); } while (0)

    issue(0); issue(1);   // this half's tiles 0,1

    for (int k = 0; k < 7; ++k) {
        WAITV0; BARRIER();
        issue(2); issue(3);
        window(0, 1);
        WAITV0; BARRIER();
        issue(0); issue(1);
        window(2, 3);
    }
    WAITV0; BARRIER();
    issue(2); issue(3);
    window(0, 1);
    WAITV0; BARRIER();
    window(2, 3);

    // ---- split-K merge + epilogue ----
    // kg1 publishes (o, lacc) via LDS (reusing the ring buffers); kg0 adds, divides
    // by the combined l, stores. Swizzled word offsets keep ds_*_b128 16B-aligned and
    // spread banks (~8-way, once -- negligible).
    float* Mo = (float*)&Kt[0][0][0];   // 256 slots x 64 words (o partials)   = 64 KB
    float* Ml = (float*)&Vt[0][0][0];   // 256 slots x 4  words (lacc partials) = 4 KB
    const int slot = qg * 64 + lane;

    __syncthreads();   // all computes done before overwriting ring buffers
    if (kg == 1) {
        float* p = Mo + slot * 64;
        #pragma unroll
        for (int g = 0; g < 4; ++g)
            #pragma unroll
            for (int mb = 0; mb < 4; ++mb) {
                const int fi = g * 4 + mb;
                *(f32x4*)(p + ((fi ^ (slot & 15)) * 4)) = o[g][mb];
            }
        f32x4 lv = (f32x4){lacc[0][0], lacc[1][0], lacc[2][0], lacc[3][0]};
        *(f32x4*)(Ml + slot * 4) = lv;
    }
    __syncthreads();   // kg1's partials visible
    if (kg == 0) {
        const float* p = Mo + slot * 64;
        const f32x4 lv = *(const f32x4*)(Ml + slot * 4);
        #pragma unroll
        for (int g = 0; g < 4; ++g) {
            const float inv = 1.0f / (lacc[g][0] + lv[g]);
            const int qrow = qbase + qg * 64 + g * 16 + lm;
            float* op = out + ((size_t)qrow * H + h) * D + quad * 4;
            #pragma unroll
            for (int mb = 0; mb < 4; ++mb) {
                const int fi = g * 4 + mb;
                const f32x4 ob = *(const f32x4*)(p + ((fi ^ (slot & 15)) * 4));
                f4v w;
                #pragma unroll
                for (int r = 0; r < 4; ++r) w[r] = (o[g][mb][r] + ob[r]) * inv;
                *(f4v*)(op + mb * 16) = w;
            }
        }
    }
}

extern "C" void kernel_launch(void* const* d_in, const int* in_sizes, int n_in,
                              void* d_out, int out_size, void* d_ws, size_t ws_size,
                              hipStream_t stream) {
    const float* q = (const float*)d_in[0];
    const float* k = (const float*)d_in[1];
    const float* v = (const float*)d_in[2];
    float* out = (float*)d_out;

    short* kb = (short*)d_ws;                        // 8 MB bf16 K [h][n][d]
    short* vt = kb + (size_t)H * NSEQ * D;           // 8 MB bf16 V^T [h][d][n'] (sigma-permuted)

    prep<<<dim3(NSEQ / 64, H), dim3(256), 0, stream>>>(k, v, kb, vt);
    attn_fwd<<<dim3((NSEQ / BM) * H), dim3(512), 0, stream>>>(q, kb, vt, out);
}

// Round 9
// 168.708 us; speedup vs baseline: 1.0069x; 1.0069x over previous
//
#include <hip/hip_runtime.h>
#include <hip/hip_bf16.h>

#define H 16
#define D 64
#define NSEQ 4096
#define BM 256         // Q rows per block (4 q-groups x 64 rows)
#define BN 64          // keys per tile
#define NT (NSEQ / BN) // 64 tiles total
#define NTH (NT / 2)   // 32 tiles per key-half

typedef __attribute__((ext_vector_type(8))) short bf16x8;   // MFMA A/B frag (4 VGPRs)
typedef __attribute__((ext_vector_type(4))) short short4v;
typedef __attribute__((ext_vector_type(4))) float f32x4;    // MFMA C/D frag
typedef __attribute__((ext_vector_type(4))) float f4v;

union BF8 { bf16x8 v; unsigned u[4]; };
union S4  { short4v s; unsigned u[2]; };

// pack two fp32 -> one dword of bf16 (RNE), v_cvt_pk_bf16_f32 on gfx950
static __device__ __forceinline__ unsigned pk2(float lo, float hi) {
    __hip_bfloat162 h = __float22bfloat162_rn(float2{lo, hi});
    unsigned u;
    __builtin_memcpy(&u, &h, 4);
    return u;
}

static __device__ __forceinline__ float fexp2(float x) {
#if __has_builtin(__builtin_amdgcn_exp2f)
    return __builtin_amdgcn_exp2f(x);
#else
    return exp2f(x);
#endif
}

#define TO_GBL(p) ((const __attribute__((address_space(1))) int*)(unsigned long long)(p))
#define TO_LDS(p) ((__attribute__((address_space(3))) int*)(unsigned int)(unsigned long long)(p))

// ---- preprocess: K fp32 [n][h][d] -> bf16 [h][n][d];
//      V fp32 [n][h][d] -> bf16 V^T [h][d][n'] (sigma key-permutation per 32-group) ----
__global__ void prep(const float* __restrict__ k, const float* __restrict__ v,
                     short* __restrict__ kb, short* __restrict__ vt) {
    __shared__ short L[64 * 72];
    const int h = blockIdx.y, n0 = blockIdx.x * 64, t = threadIdx.x;
    const int rw = t >> 4, c4 = (t & 15) * 4;
    #pragma unroll
    for (int it = 0; it < 4; ++it) {
        const int row = rw + it * 16;
        const size_t gro = ((size_t)(n0 + row) * H + h) * D + c4;
        f4v kf = *(const f4v*)(k + gro);
        S4 ks;
        ks.u[0] = pk2(kf[0], kf[1]);
        ks.u[1] = pk2(kf[2], kf[3]);
        *(short4v*)(kb + ((size_t)h * NSEQ + n0 + row) * D + c4) = ks.s;

        f4v vf = *(const f4v*)(v + gro);
        S4 vs;
        vs.u[0] = pk2(vf[0], vf[1]);
        vs.u[1] = pk2(vf[2], vf[3]);
        *(short4v*)&L[row * 72 + c4] = vs.s;
    }
    __syncthreads();
    // 4x4 in-register transpose: thread t owns seq-slots r0..r0+3 x d0..d0+3
    const int tr = t & 15, tc = t >> 4;
    const int r0 = tr * 4, d0 = tc * 4;
    short4v ra[4];
    #pragma unroll
    for (int i = 0; i < 4; ++i) {
        const int s = r0 + i, s32 = s & 31, base32 = (s >> 5) * 32;
        const int phys = base32 + ((s32 >> 3) * 4 + (s32 & 3) + 16 * ((s32 >> 2) & 1));
        ra[i] = *(const short4v*)&L[phys * 72 + d0];
    }
    #pragma unroll
    for (int jj = 0; jj < 4; ++jj) {
        short4v o4 = (short4v){ra[0][jj], ra[1][jj], ra[2][jj], ra[3][jj]};
        *(short4v*)(vt + ((size_t)(h * D + d0 + jj)) * NSEQ + n0 + r0) = o4;
    }
}

// ---------------- main attention kernel ----------------
// R9 = R7/R8 body with the register ceiling ACTUALLY raised (one token changed).
// Empirical launch-bounds semantics from R5/R7/R8 on this toolchain: second arg = min
// BLOCKS/CU. (512,2) -> 16 waves/CU -> 4 waves/EU -> VGPR cap 512/4 = 128 (observed:
// VGPR pinned at exactly 128 in R7 AND R8, with scratch spill WRITE_SIZE 22 MB).
// amdgpu_waves_per_eu(2) was ignored (R8 codegen identical to R7). Here: (512,1) ->
// 1 block/CU (which the 128 KB LDS forces anyway) -> 2 waves/EU -> cap 256. Runtime
// occupancy unchanged (LDS-limited); only the allocator's budget moves. This is the
// clean test of the delayed-PV interleave:
//   qk(a); sm(a)->pbA; qk(b); { sm(b) interleaved with pv(a) }; pv(b)
// Tripwires: VGPR_Count must leave 128; WRITE_SIZE must return to 16384 KB.
__global__ __launch_bounds__(512, 1)
void attn_fwd(const float* __restrict__ q, const short* __restrict__ kb,
              const short* __restrict__ vtb, float* __restrict__ out)
{
    // XCD swizzle (T1, verified FETCH 73.8->16.5 MB): 256 blocks, (lin&7)=XCD,
    // 2 heads per XCD -> 2 MB K/V working set <= 4 MB L2. Bijective: 256%8==0.
    const int lin   = blockIdx.x;
    const int idx   = lin >> 3;              // 0..31 within this XCD
    const int h     = (lin & 7) * 2 + (idx >> 4);
    const int qbase = (idx & 15) * BM;

    const int tid   = threadIdx.x;
    const int wave  = tid >> 6;              // 0..7
    const int kg    = wave >> 2;             // key-half: 0 -> tiles 0..31, 1 -> 32..63
    const int qg    = wave & 3;              // q-group / stager index within half
    const int lane  = tid & 63;
    const int lm    = lane & 15;
    const int quad  = lane >> 4;
    const int sw    = lm & 7;
    const int T0    = kg * NTH;              // tile offset of this key-half

    // per-key-half ring-4 buffers: 2 x (4x8KB K + 4x8KB V) = 128 KB
    __shared__ short Kt[2][4][BN * D];   // [kg][slot][key*64+d], 16B-chunk XOR-swizzled
    __shared__ short Vt[2][4][BN * D];   // [kg][slot][d*64+key'], sigma-permuted, XOR-swizzled

    const float c1 = 0.18033688011112042f;   // 0.125 * log2(e), folded into Q

    // Q fragments (B-operand of S^T mfma): B[n=lm][k = kc*32 + quad*8 + j], pre-scaled
    bf16x8 bq[4][2];
    #pragma unroll
    for (int g = 0; g < 4; ++g) {
        const int qrow = qbase + qg * 64 + g * 16 + lm;
        #pragma unroll
        for (int kc = 0; kc < 2; ++kc) {
            const float* qp = q + ((size_t)qrow * H + h) * D + kc * 32 + quad * 8;
            f4v q0 = *(const f4v*)qp;
            f4v q1 = *(const f4v*)(qp + 4);
            BF8 b;
            b.u[0] = pk2(q0[0] * c1, q0[1] * c1); b.u[1] = pk2(q0[2] * c1, q0[3] * c1);
            b.u[2] = pk2(q1[0] * c1, q1[1] * c1); b.u[3] = pk2(q1[2] * c1, q1[3] * c1);
            bq[g][kc] = b.v;
        }
    }

    // all-ones A fragment for the l-accumulating MFMA (bf16 1.0 = 0x3F80)
    BF8 ones;
    ones.u[0] = ones.u[1] = ones.u[2] = ones.u[3] = 0x3F803F80u;

    const f32x4 fz = (f32x4){0.f, 0.f, 0.f, 0.f};
    f32x4 o[4][4];   // O^T accum: lane holds d=mb*16+quad*4+r, q=g*16+lm
    #pragma unroll
    for (int g = 0; g < 4; ++g)
        #pragma unroll
        for (int mb = 0; mb < 4; ++mb) o[g][mb] = fz;
    f32x4 lacc[4];   // l accum via ones-MFMA: each lane's [r] = full partial l
    lacc[0] = fz; lacc[1] = fz; lacc[2] = fz; lacc[3] = fz;

    // staging (R2's verified pattern, stager = qg): 512 x 16B chunks per 8KB buffer;
    // chunk ci -> row ci>>3, pos ci&7, source column chunk = pos ^ (row&7)
    const int ci0 = (qg * 2 + 0) * 64 + lane;
    const int ci1 = (qg * 2 + 1) * 64 + lane;
    const int kr0 = ci0 >> 3, kp0 = (ci0 & 7) ^ (kr0 & 7);
    const int kr1 = ci1 >> 3, kp1 = (ci1 & 7) ^ (kr1 & 7);

    const short* kh = kb  + (size_t)h * NSEQ * D;
    const short* vh = vtb + (size_t)h * D * NSEQ;
    const short* pkA = kh + (size_t)(T0 * BN + kr0) * D + kp0 * 8;
    const short* pkB = kh + (size_t)(T0 * BN + kr1) * D + kp1 * 8;
    const short* pvA = vh + (size_t)kr0 * NSEQ + T0 * BN + kp0 * 8;
    const short* pvB = vh + (size_t)kr1 * NSEQ + T0 * BN + kp1 * 8;

    auto issue = [&](int b) {
        __builtin_amdgcn_global_load_lds(TO_GBL(pkA), TO_LDS(&Kt[kg][b][(qg * 2 + 0) * 512]), 16, 0, 0);
        __builtin_amdgcn_global_load_lds(TO_GBL(pkB), TO_LDS(&Kt[kg][b][(qg * 2 + 1) * 512]), 16, 0, 0);
        __builtin_amdgcn_global_load_lds(TO_GBL(pvA), TO_LDS(&Vt[kg][b][(qg * 2 + 0) * 512]), 16, 0, 0);
        __builtin_amdgcn_global_load_lds(TO_GBL(pvB), TO_LDS(&Vt[kg][b][(qg * 2 + 1) * 512]), 16, 0, 0);
        pkA += BN * D; pkB += BN * D; pvA += BN; pvB += BN;
    };

    const int posK0 = ((0 + quad) ^ sw) * 8;
    const int posK1 = ((4 + quad) ^ sw) * 8;

    // ---- pipeline stages ----
    // qk: 8 ds_read_b128 + 32 MFMA (K-frag reuse across 4 g's)
    auto qk = [&](int b, f32x4 (&st)[4][4]) {
        const short* K_ = Kt[kg][b];
        bf16x8 kf0[4], kf1[4];
        #pragma unroll
        for (int nb = 0; nb < 4; ++nb) {
            kf0[nb] = *(const bf16x8*)&K_[(nb * 16 + lm) * 64 + posK0];
            kf1[nb] = *(const bf16x8*)&K_[(nb * 16 + lm) * 64 + posK1];
        }
        #pragma unroll
        for (int g = 0; g < 4; ++g)
            #pragma unroll
            for (int nb = 0; nb < 4; ++nb) {
                st[g][nb] = __builtin_amdgcn_mfma_f32_16x16x32_bf16(kf0[nb], bq[g][0], fz, 0, 0, 0);
                st[g][nb] = __builtin_amdgcn_mfma_f32_16x16x32_bf16(kf1[nb], bq[g][1], st[g][nb], 0, 0, 0);
            }
    };

    // smg: exp+pack for ONE g (16 exp2 on trans + 8 cvt_pk on VALU)
    auto smg = [&](f32x4 (&st)[4][4], BF8 (&pb)[4][2], int g) {
        #pragma unroll
        for (int nb = 0; nb < 4; ++nb)
            #pragma unroll
            for (int r = 0; r < 4; ++r)
                st[g][nb][r] = fexp2(st[g][nb][r]);
        #pragma unroll
        for (int c = 0; c < 2; ++c) {
            pb[g][c].u[0] = pk2(st[g][2 * c][0],     st[g][2 * c][1]);
            pb[g][c].u[1] = pk2(st[g][2 * c][2],     st[g][2 * c][3]);
            pb[g][c].u[2] = pk2(st[g][2 * c + 1][0], st[g][2 * c + 1][1]);
            pb[g][c].u[3] = pk2(st[g][2 * c + 1][2], st[g][2 * c + 1][3]);
        }
    };

    // pvc: one c-half of PV: 4 l-acc MFMA + 4 ds_read_b128 + 16 PV MFMA
    auto pvc = [&](int b, BF8 (&pb)[4][2], int c) {
        const short* V_ = Vt[kg][b];
        #pragma unroll
        for (int g = 0; g < 4; ++g)
            lacc[g] = __builtin_amdgcn_mfma_f32_16x16x32_bf16(ones.v, pb[g][c].v, lacc[g], 0, 0, 0);
        const int pos = ((c * 4 + quad) ^ sw) * 8;
        #pragma unroll
        for (int mb = 0; mb < 4; ++mb) {
            bf16x8 vf = *(const bf16x8*)&V_[(mb * 16 + lm) * 64 + pos];
            #pragma unroll
            for (int g = 0; g < 4; ++g)
                o[g][mb] = __builtin_amdgcn_mfma_f32_16x16x32_bf16(vf, pb[g][c].v, o[g][mb], 0, 0, 0);
        }
    };

    // delayed-PV window: only cross-stage carry is pbA (32 VGPR). st is reused for
    // both tiles (SSA renaming, no forced serialization). sm(b) bursts sit between
    // pv(a) halves -> VALU work always has independent MFMA work adjacent.
    auto window = [&](int a, int b) {
        f32x4 st[4][4];
        BF8 pbA[4][2], pbB[4][2];
        qk(a, st);
        smg(st, pbA, 0); smg(st, pbA, 1); smg(st, pbA, 2); smg(st, pbA, 3);
        qk(b, st);
        smg(st, pbB, 0); smg(st, pbB, 1);
        pvc(a, pbA, 0);
        smg(st, pbB, 2); smg(st, pbB, 3);
        pvc(a, pbA, 1);
        pvc(b, pbB, 0);
        pvc(b, pbB, 1);
    };

    // ---- pair-window schedule (one barrier + one vmcnt(0) per two tiles), 32 tiles ----
#define WAITV0 asm volatile("s_waitcnt vmcnt(0)" ::: "memory")
#define BARRIER() do { __builtin_amdgcn_s_barrier(); asm volatile("" ::: "memory"); } while (0)

    issue(0); issue(1);   // this half's tiles 0,1

    for (int k = 0; k < 7; ++k) {
        WAITV0; BARRIER();
        issue(2); issue(3);
        window(0, 1);
        WAITV0; BARRIER();
        issue(0); issue(1);
        window(2, 3);
    }
    WAITV0; BARRIER();
    issue(2); issue(3);
    window(0, 1);
    WAITV0; BARRIER();
    window(2, 3);

    // ---- split-K merge + epilogue ----
    // kg1 publishes (o, lacc) via LDS (reusing the ring buffers); kg0 adds, divides
    // by the combined l, stores. Swizzled word offsets keep ds_*_b128 16B-aligned and
    // spread banks (~8-way, once -- negligible).
    float* Mo = (float*)&Kt[0][0][0];   // 256 slots x 64 words (o partials)   = 64 KB
    float* Ml = (float*)&Vt[0][0][0];   // 256 slots x 4  words (lacc partials) = 4 KB
    const int slot = qg * 64 + lane;

    __syncthreads();   // all computes done before overwriting ring buffers
    if (kg == 1) {
        float* p = Mo + slot * 64;
        #pragma unroll
        for (int g = 0; g < 4; ++g)
            #pragma unroll
            for (int mb = 0; mb < 4; ++mb) {
                const int fi = g * 4 + mb;
                *(f32x4*)(p + ((fi ^ (slot & 15)) * 4)) = o[g][mb];
            }
        f32x4 lv = (f32x4){lacc[0][0], lacc[1][0], lacc[2][0], lacc[3][0]};
        *(f32x4*)(Ml + slot * 4) = lv;
    }
    __syncthreads();   // kg1's partials visible
    if (kg == 0) {
        const float* p = Mo + slot * 64;
        const f32x4 lv = *(const f32x4*)(Ml + slot * 4);
        #pragma unroll
        for (int g = 0; g < 4; ++g) {
            const float inv = 1.0f / (lacc[g][0] + lv[g]);
            const int qrow = qbase + qg * 64 + g * 16 + lm;
            float* op = out + ((size_t)qrow * H + h) * D + quad * 4;
            #pragma unroll
            for (int mb = 0; mb < 4; ++mb) {
                const int fi = g * 4 + mb;
                const f32x4 ob = *(const f32x4*)(p + ((fi ^ (slot & 15)) * 4));
                f4v w;
                #pragma unroll
                for (int r = 0; r < 4; ++r) w[r] = (o[g][mb][r] + ob[r]) * inv;
                *(f4v*)(op + mb * 16) = w;
            }
        }
    }
}

extern "C" void kernel_launch(void* const* d_in, const int* in_sizes, int n_in,
                              void* d_out, int out_size, void* d_ws, size_t ws_size,
                              hipStream_t stream) {
    const float* q = (const float*)d_in[0];
    const float* k = (const float*)d_in[1];
    const float* v = (const float*)d_in[2];
    float* out = (float*)d_out;

    short* kb = (short*)d_ws;                        // 8 MB bf16 K [h][n][d]
    short* vt = kb + (size_t)H * NSEQ * D;           // 8 MB bf16 V^T [h][d][n'] (sigma-permuted)

    prep<<<dim3(NSEQ / 64, H), dim3(256), 0, stream>>>(k, v, kb, vt);
    attn_fwd<<<dim3((NSEQ / BM) * H), dim3(512), 0, stream>>>(q, kb, vt, out);
}

// Round 11
// 165.397 us; speedup vs baseline: 1.0270x; 1.0200x over previous
//
#include <hip/hip_runtime.h>
#include <hip/hip_bf16.h>

#define H 16
#define D 64
#define NSEQ 4096
#define BM 128         // Q rows per block (2 q-groups x 64 rows)
#define BN 64          // keys per tile
#define NT (NSEQ / BN) // 64 tiles total
#define NTH (NT / 2)   // 32 tiles per key-half

typedef __attribute__((ext_vector_type(8))) short bf16x8;   // MFMA A/B frag (4 VGPRs)
typedef __attribute__((ext_vector_type(4))) short short4v;
typedef __attribute__((ext_vector_type(4))) float f32x4;    // MFMA C/D frag
typedef __attribute__((ext_vector_type(4))) float f4v;

union BF8 { bf16x8 v; unsigned u[4]; };
union S4  { short4v s; unsigned u[2]; };

// pack two fp32 -> one dword of bf16 (RNE), v_cvt_pk_bf16_f32 on gfx950
static __device__ __forceinline__ unsigned pk2(float lo, float hi) {
    __hip_bfloat162 h = __float22bfloat162_rn(float2{lo, hi});
    unsigned u;
    __builtin_memcpy(&u, &h, 4);
    return u;
}

static __device__ __forceinline__ float fexp2(float x) {
#if __has_builtin(__builtin_amdgcn_exp2f)
    return __builtin_amdgcn_exp2f(x);
#else
    return exp2f(x);
#endif
}

#define TO_GBL(p) ((const __attribute__((address_space(1))) int*)(unsigned long long)(p))
#define TO_LDS(p) ((__attribute__((address_space(3))) int*)(unsigned int)(unsigned long long)(p))

// ---- preprocess: K fp32 [n][h][d] -> bf16 [h][n][d];
//      V fp32 [n][h][d] -> bf16 V^T [h][d][n'] (sigma key-permutation per 32-group) ----
__global__ void prep(const float* __restrict__ k, const float* __restrict__ v,
                     short* __restrict__ kb, short* __restrict__ vt) {
    __shared__ short L[64 * 72];
    const int h = blockIdx.y, n0 = blockIdx.x * 64, t = threadIdx.x;
    const int rw = t >> 4, c4 = (t & 15) * 4;
    #pragma unroll
    for (int it = 0; it < 4; ++it) {
        const int row = rw + it * 16;
        const size_t gro = ((size_t)(n0 + row) * H + h) * D + c4;
        f4v kf = *(const f4v*)(k + gro);
        S4 ks;
        ks.u[0] = pk2(kf[0], kf[1]);
        ks.u[1] = pk2(kf[2], kf[3]);
        *(short4v*)(kb + ((size_t)h * NSEQ + n0 + row) * D + c4) = ks.s;

        f4v vf = *(const f4v*)(v + gro);
        S4 vs;
        vs.u[0] = pk2(vf[0], vf[1]);
        vs.u[1] = pk2(vf[2], vf[3]);
        *(short4v*)&L[row * 72 + c4] = vs.s;
    }
    __syncthreads();
    // 4x4 in-register transpose: thread t owns seq-slots r0..r0+3 x d0..d0+3
    const int tr = t & 15, tc = t >> 4;
    const int r0 = tr * 4, d0 = tc * 4;
    short4v ra[4];
    #pragma unroll
    for (int i = 0; i < 4; ++i) {
        const int s = r0 + i, s32 = s & 31, base32 = (s >> 5) * 32;
        const int phys = base32 + ((s32 >> 3) * 4 + (s32 & 3) + 16 * ((s32 >> 2) & 1));
        ra[i] = *(const short4v*)&L[phys * 72 + d0];
    }
    #pragma unroll
    for (int jj = 0; jj < 4; ++jj) {
        short4v o4 = (short4v){ra[0][jj], ra[1][jj], ra[2][jj], ra[3][jj]};
        *(short4v*)(vt + ((size_t)(h * D + d0 + jj)) * NSEQ + n0 + r0) = o4;
    }
}

// ---------------- main attention kernel ----------------
// R11 = R10's two-barrier-domain partition with the staging re-expressed in the
// R5-PROVEN form: eight fully-computed per-set pointers, offset=0 on EVERY
// global_load_lds. R10's only never-before-exercised mechanism was a non-zero
// `offset` arg on global_load_lds (K sets at offset 1024/2048/3072); on CDNA the
// buffer/global-to-LDS immediate may apply to the LDS address (LDS_ADDR = M0 +
// inst_offset + lane*size), not the global address -- which would misplace 3/4 of
// the K tile rows and produce exactly R10's 0.237 absmax. Everything else in R10
// re-derived clean. This round eliminates the offset mechanism entirely.
//
// Partition (unchanged from R10's intent): BM=128, 256-thread blocks (2 kg x 2 qg,
// 64 q per wave), ring-2 buffers, 64 KB LDS -> 2 independent blocks/CU with their
// own barriers. Per-CU work, LDS demand, MFMA demand, occupancy identical to R5
// (90.2 us) -- but co-resident blocks drift, so one block's MFMA phase overlaps the
// other's exp/VALU phase. Tripwires: VGPR ~116, WRITE_SIZE=16384 KB, LDS=65536.
__global__ __launch_bounds__(256, 2)
void attn_fwd(const float* __restrict__ q, const short* __restrict__ kb,
              const short* __restrict__ vtb, float* __restrict__ out)
{
    // XCD swizzle (T1, verified): 512 blocks, (lin&7)=XCD, 2 heads per XCD ->
    // 2 MB K/V working set <= 4 MB L2. Bijective: 512 % 8 == 0.
    const int lin   = blockIdx.x;
    const int idx   = lin >> 3;              // 0..63 within this XCD
    const int h     = (lin & 7) * 2 + (idx >> 5);
    const int qbase = (idx & 31) * BM;

    const int tid   = threadIdx.x;
    const int wave  = tid >> 6;              // 0..3
    const int kg    = wave >> 1;             // key-half: 0 -> tiles 0..31, 1 -> 32..63
    const int qg    = wave & 1;              // q-group / stager index within half
    const int lane  = tid & 63;
    const int lm    = lane & 15;
    const int quad  = lane >> 4;
    const int sw    = lm & 7;
    const int T0    = kg * NTH;              // tile offset of this key-half

    // per-key-half ring-2 buffers: 2 x (2x8KB K + 2x8KB V) = 64 KB -> 2 blocks/CU
    __shared__ short Kt[2][2][BN * D];   // [kg][slot][key*64+d], 16B-chunk XOR-swizzled
    __shared__ short Vt[2][2][BN * D];   // [kg][slot][d*64+key'], sigma-permuted, XOR-swizzled

    const float c1 = 0.18033688011112042f;   // 0.125 * log2(e), folded into Q

    // Q fragments (B-operand of S^T mfma): B[n=lm][k = kc*32 + quad*8 + j], pre-scaled
    bf16x8 bq[4][2];
    #pragma unroll
    for (int g = 0; g < 4; ++g) {
        const int qrow = qbase + qg * 64 + g * 16 + lm;
        #pragma unroll
        for (int kc = 0; kc < 2; ++kc) {
            const float* qp = q + ((size_t)qrow * H + h) * D + kc * 32 + quad * 8;
            f4v q0 = *(const f4v*)qp;
            f4v q1 = *(const f4v*)(qp + 4);
            BF8 b;
            b.u[0] = pk2(q0[0] * c1, q0[1] * c1); b.u[1] = pk2(q0[2] * c1, q0[3] * c1);
            b.u[2] = pk2(q1[0] * c1, q1[1] * c1); b.u[3] = pk2(q1[2] * c1, q1[3] * c1);
            bq[g][kc] = b.v;
        }
    }

    // all-ones A fragment for the l-accumulating MFMA (bf16 1.0 = 0x3F80)
    BF8 ones;
    ones.u[0] = ones.u[1] = ones.u[2] = ones.u[3] = 0x3F803F80u;

    const f32x4 fz = (f32x4){0.f, 0.f, 0.f, 0.f};
    f32x4 o[4][4];   // O^T accum: lane holds d=mb*16+quad*4+r, q=g*16+lm
    #pragma unroll
    for (int g = 0; g < 4; ++g)
        #pragma unroll
        for (int mb = 0; mb < 4; ++mb) o[g][mb] = fz;
    f32x4 lacc[4];   // l accum via ones-MFMA: each lane's [r] = full partial l
    lacc[0] = fz; lacc[1] = fz; lacc[2] = fz; lacc[3] = fz;

    // staging (R5's proven per-set recipe, 4 sets per wave): buffer = 512 x 16B
    // chunks; chunk ci -> row ci>>3, pos ci&7, source col chunk = pos ^ (row&7).
    // This wave's sets: ci_j = qg*256 + j*64 + lane, j = 0..3.
    const int ci0 = qg * 256 + 0 * 64 + lane;
    const int ci1 = qg * 256 + 1 * 64 + lane;
    const int ci2 = qg * 256 + 2 * 64 + lane;
    const int ci3 = qg * 256 + 3 * 64 + lane;
    const int kr0 = ci0 >> 3, kp0 = (ci0 & 7) ^ (kr0 & 7);
    const int kr1 = ci1 >> 3, kp1 = (ci1 & 7) ^ (kr1 & 7);
    const int kr2 = ci2 >> 3, kp2 = (ci2 & 7) ^ (kr2 & 7);
    const int kr3 = ci3 >> 3, kp3 = (ci3 & 7) ^ (kr3 & 7);

    const short* kh = kb  + (size_t)h * NSEQ * D;
    const short* vh = vtb + (size_t)h * D * NSEQ;
    const short* pk0 = kh + (size_t)(T0 * BN + kr0) * D + kp0 * 8;
    const short* pk1 = kh + (size_t)(T0 * BN + kr1) * D + kp1 * 8;
    const short* pk2_ = kh + (size_t)(T0 * BN + kr2) * D + kp2 * 8;
    const short* pk3 = kh + (size_t)(T0 * BN + kr3) * D + kp3 * 8;
    const short* pv0 = vh + (size_t)kr0 * NSEQ + T0 * BN + kp0 * 8;
    const short* pv1 = vh + (size_t)kr1 * NSEQ + T0 * BN + kp1 * 8;
    const short* pv2 = vh + (size_t)kr2 * NSEQ + T0 * BN + kp2 * 8;
    const short* pv3 = vh + (size_t)kr3 * NSEQ + T0 * BN + kp3 * 8;

    auto issue = [&](int b) {
        short* kd = &Kt[kg][b][qg * 2048];      // set j dest: chunk qg*256 + j*64
        short* vd = &Vt[kg][b][qg * 2048];
        __builtin_amdgcn_global_load_lds(TO_GBL(pk0), TO_LDS(kd +    0), 16, 0, 0);
        __builtin_amdgcn_global_load_lds(TO_GBL(pk1), TO_LDS(kd +  512), 16, 0, 0);
        __builtin_amdgcn_global_load_lds(TO_GBL(pk2_), TO_LDS(kd + 1024), 16, 0, 0);
        __builtin_amdgcn_global_load_lds(TO_GBL(pk3), TO_LDS(kd + 1536), 16, 0, 0);
        __builtin_amdgcn_global_load_lds(TO_GBL(pv0), TO_LDS(vd +    0), 16, 0, 0);
        __builtin_amdgcn_global_load_lds(TO_GBL(pv1), TO_LDS(vd +  512), 16, 0, 0);
        __builtin_amdgcn_global_load_lds(TO_GBL(pv2), TO_LDS(vd + 1024), 16, 0, 0);
        __builtin_amdgcn_global_load_lds(TO_GBL(pv3), TO_LDS(vd + 1536), 16, 0, 0);
        pk0 += BN * D; pk1 += BN * D; pk2_ += BN * D; pk3 += BN * D;
        pv0 += BN; pv1 += BN; pv2 += BN; pv3 += BN;
    };

    const int posK0 = ((0 + quad) ^ sw) * 8;
    const int posK1 = ((4 + quad) ^ sw) * 8;

    // R5's verified compute body (64 q/wave, K-frag reuse across 4 g's)
    auto compute = [&](int b) {
        const short* K_ = Kt[kg][b];
        const short* V_ = Vt[kg][b];

        bf16x8 kf0[4], kf1[4];
        #pragma unroll
        for (int nb = 0; nb < 4; ++nb) {
            kf0[nb] = *(const bf16x8*)&K_[(nb * 16 + lm) * 64 + posK0];
            kf1[nb] = *(const bf16x8*)&K_[(nb * 16 + lm) * 64 + posK1];
        }

        BF8 pb[4][2];
        #pragma unroll
        for (int g = 0; g < 4; ++g) {
            f32x4 st[4];
            #pragma unroll
            for (int nb = 0; nb < 4; ++nb) {
                st[nb] = __builtin_amdgcn_mfma_f32_16x16x32_bf16(kf0[nb], bq[g][0], fz, 0, 0, 0);
                st[nb] = __builtin_amdgcn_mfma_f32_16x16x32_bf16(kf1[nb], bq[g][1], st[nb], 0, 0, 0);
            }
            #pragma unroll
            for (int nb = 0; nb < 4; ++nb)
                #pragma unroll
                for (int r = 0; r < 4; ++r)
                    st[nb][r] = fexp2(st[nb][r]);
            #pragma unroll
            for (int c = 0; c < 2; ++c) {
                pb[g][c].u[0] = pk2(st[2 * c][0],     st[2 * c][1]);
                pb[g][c].u[1] = pk2(st[2 * c][2],     st[2 * c][3]);
                pb[g][c].u[2] = pk2(st[2 * c + 1][0], st[2 * c + 1][1]);
                pb[g][c].u[3] = pk2(st[2 * c + 1][2], st[2 * c + 1][3]);
            }
        }

        #pragma unroll
        for (int c = 0; c < 2; ++c)
            #pragma unroll
            for (int g = 0; g < 4; ++g)
                lacc[g] = __builtin_amdgcn_mfma_f32_16x16x32_bf16(ones.v, pb[g][c].v, lacc[g], 0, 0, 0);

        #pragma unroll
        for (int c = 0; c < 2; ++c) {
            const int pos = ((c * 4 + quad) ^ sw) * 8;
            #pragma unroll
            for (int mb = 0; mb < 4; ++mb) {
                bf16x8 vf = *(const bf16x8*)&V_[(mb * 16 + lm) * 64 + pos];
                #pragma unroll
                for (int g = 0; g < 4; ++g)
                    o[g][mb] = __builtin_amdgcn_mfma_f32_16x16x32_bf16(vf, pb[g][c].v, o[g][mb], 0, 0, 0);
            }
        }
    };

    // ---- ring-2 schedule: one barrier + one vmcnt(0) per tile, 32 tiles per kg ----
    // At the barrier for tile t: slot (t+1)&1 was computed by all 4 waves last
    // iteration (free to overwrite), and this wave's tile-t loads (issued last
    // iteration) are drained by vmcnt(0).
#define WAITV0 asm volatile("s_waitcnt vmcnt(0)" ::: "memory")
#define BARRIER() do { __builtin_amdgcn_s_barrier(); asm volatile("" ::: "memory"); } while (0)

    issue(0);
    for (int t = 0; t < NTH - 1; ++t) {
        WAITV0; BARRIER();
        issue((t + 1) & 1);
        compute(t & 1);
    }
    WAITV0; BARRIER();
    compute((NTH - 1) & 1);

    // ---- split-K merge + epilogue ----
    // kg1 (2 waves) publishes (o, lacc) via LDS (reusing ring buffers); kg0 adds,
    // divides by combined l, stores. 128 slots x 64 floats = 32 KB = all of Kt.
    float* Mo = (float*)&Kt[0][0][0];   // 128 slots x 64 words (o partials)    = 32 KB
    float* Ml = (float*)&Vt[0][0][0];   // 128 slots x 4  words (lacc partials) =  2 KB
    const int slot = qg * 64 + lane;

    __syncthreads();   // all computes done before overwriting ring buffers
    if (kg == 1) {
        float* p = Mo + slot * 64;
        #pragma unroll
        for (int g = 0; g < 4; ++g)
            #pragma unroll
            for (int mb = 0; mb < 4; ++mb) {
                const int fi = g * 4 + mb;
                *(f32x4*)(p + ((fi ^ (slot & 15)) * 4)) = o[g][mb];
            }
        f32x4 lv = (f32x4){lacc[0][0], lacc[1][0], lacc[2][0], lacc[3][0]};
        *(f32x4*)(Ml + slot * 4) = lv;
    }
    __syncthreads();   // kg1's partials visible
    if (kg == 0) {
        const float* p = Mo + slot * 64;
        const f32x4 lv = *(const f32x4*)(Ml + slot * 4);
        #pragma unroll
        for (int g = 0; g < 4; ++g) {
            const float inv = 1.0f / (lacc[g][0] + lv[g]);
            const int qrow = qbase + qg * 64 + g * 16 + lm;
            float* op = out + ((size_t)qrow * H + h) * D + quad * 4;
            #pragma unroll
            for (int mb = 0; mb < 4; ++mb) {
                const int fi = g * 4 + mb;
                const f32x4 ob = *(const f32x4*)(p + ((fi ^ (slot & 15)) * 4));
                f4v w;
                #pragma unroll
                for (int r = 0; r < 4; ++r) w[r] = (o[g][mb][r] + ob[r]) * inv;
                *(f4v*)(op + mb * 16) = w;
            }
        }
    }
}

extern "C" void kernel_launch(void* const* d_in, const int* in_sizes, int n_in,
                              void* d_out, int out_size, void* d_ws, size_t ws_size,
                              hipStream_t stream) {
    const float* q = (const float*)d_in[0];
    const float* k = (const float*)d_in[1];
    const float* v = (const float*)d_in[2];
    float* out = (float*)d_out;

    short* kb = (short*)d_ws;                        // 8 MB bf16 K [h][n][d]
    short* vt = kb + (size_t)H * NSEQ * D;           // 8 MB bf16 V^T [h][d][n'] (sigma-permuted)

    prep<<<dim3(NSEQ / 64, H), dim3(256), 0, stream>>>(k, v, kb, vt);
    attn_fwd<<<dim3((NSEQ / BM) * H), dim3(256), 0, stream>>>(q, kb, vt, out);
}

// Round 12
// 161.991 us; speedup vs baseline: 1.0486x; 1.0210x over previous
//
#include <hip/hip_runtime.h>
#include <hip/hip_bf16.h>

#define H 16
#define D 64
#define NSEQ 4096
#define BM 128         // Q rows per block (2 q-groups x 64 rows)
#define BN 64          // keys per tile
#define NT (NSEQ / BN) // 64 tiles total
#define NTH (NT / 2)   // 32 tiles per key-half

typedef __attribute__((ext_vector_type(8))) short bf16x8;   // MFMA A/B frag (4 VGPRs)
typedef __attribute__((ext_vector_type(4))) short short4v;
typedef __attribute__((ext_vector_type(4))) float f32x4;    // MFMA C/D frag
typedef __attribute__((ext_vector_type(4))) float f4v;

union BF8 { bf16x8 v; unsigned u[4]; };
union S4  { short4v s; unsigned u[2]; };

// pack two fp32 -> one dword of bf16 (RNE), v_cvt_pk_bf16_f32 on gfx950
static __device__ __forceinline__ unsigned pk2(float lo, float hi) {
    __hip_bfloat162 h = __float22bfloat162_rn(float2{lo, hi});
    unsigned u;
    __builtin_memcpy(&u, &h, 4);
    return u;
}

static __device__ __forceinline__ float fexp2(float x) {
#if __has_builtin(__builtin_amdgcn_exp2f)
    return __builtin_amdgcn_exp2f(x);
#else
    return exp2f(x);
#endif
}

#define TO_GBL(p) ((const __attribute__((address_space(1))) int*)(unsigned long long)(p))
#define TO_LDS(p) ((__attribute__((address_space(3))) int*)(unsigned int)(unsigned long long)(p))

// ---- preprocess (R12 rewrite: no LDS, 16B accesses both sides) ----
// K fp32 [n][h][d] -> bf16 [h][n][d]; V fp32 [n][h][d] -> bf16 V^T [h][d][n']
// with the SAME sigma key-permutation per 64-group as R0-R11's prep:
//   vt[h][d][n0 + s] = bf16(V[n0 + phys(s)][h][d]),
//   phys(s) = (s>>5)*32 + ((s&31)>>3)*4 + (s&3) + 16*(((s&31)>>2)&1).
// Old prep's LDS transpose read (stride 36 words) was an ~8-way bank conflict and
// everything was 8B stores; here V is gathered 8 rows x 16B into registers,
// transposed 8x4->4x8 in-register, and written as 4x16B. K is a pure 16B->16B
// streaming convert. Per-element RNE conversions identical -> bit-identical output.
__global__ void prep(const float* __restrict__ k, const float* __restrict__ v,
                     short* __restrict__ kb, short* __restrict__ vt) {
    const int h = blockIdx.y, n0 = blockIdx.x * 128, t = threadIdx.x;

    // ---- K: 128 rows x 64 d per block; thread = (row-group, 8-d chunk) ----
    {
        const int rw = t >> 3;            // 0..31
        const int c8 = (t & 7) * 8;       // 0,8,...,56
        #pragma unroll
        for (int it = 0; it < 4; ++it) {
            const int row = rw + it * 32;
            const float* src = k + ((size_t)(n0 + row) * H + h) * D + c8;
            f4v a = *(const f4v*)src;
            f4v b = *(const f4v*)(src + 4);
            BF8 kk;
            kk.u[0] = pk2(a[0], a[1]); kk.u[1] = pk2(a[2], a[3]);
            kk.u[2] = pk2(b[0], b[1]); kk.u[3] = pk2(b[2], b[3]);
            *(bf16x8*)(kb + ((size_t)h * NSEQ + n0 + row) * D + c8) = kk.v;
        }
    }

    // ---- V: thread = (4-d chunk, 8-n' segment); gather 8 sigma rows, transpose ----
    {
        const int dch = t & 15;           // 0..15 -> d0 = 0..60 (read coalescing:
        const int seg = t >> 4;           //   16 lanes cover one 256B fp32 d-row)
        const int d0  = dch * 4;
        const int g64 = seg >> 3;         // which 64-row group
        const int s64b = (seg & 7) * 8;   // n' segment base within group

        f4v vv[8];
        #pragma unroll
        for (int j = 0; j < 8; ++j) {
            const int s64 = s64b + j;
            const int s32 = s64 & 31;
            const int phys = (s64 >> 5) * 32 + (s32 >> 3) * 4 + (s32 & 3) + 16 * ((s32 >> 2) & 1);
            vv[j] = *(const f4v*)(v + ((size_t)(n0 + g64 * 64 + phys) * H + h) * D + d0);
        }
        #pragma unroll
        for (int jj = 0; jj < 4; ++jj) {
            BF8 o;
            o.u[0] = pk2(vv[0][jj], vv[1][jj]);
            o.u[1] = pk2(vv[2][jj], vv[3][jj]);
            o.u[2] = pk2(vv[4][jj], vv[5][jj]);
            o.u[3] = pk2(vv[6][jj], vv[7][jj]);
            *(bf16x8*)(vt + ((size_t)(h * D + d0 + jj)) * NSEQ + n0 + g64 * 64 + s64b) = o.v;
        }
    }
}

// ---------------- main attention kernel (byte-identical to R11, 87.3 us verified) ----------------
// Two barrier domains per CU: BM=128, 256-thread blocks (2 kg x 2 qg, 64 q/wave),
// ring-2 buffers, 64 KB LDS -> 2 independent blocks/CU that drift (one block's MFMA
// phase overlaps the other's exp/VALU phase; verified +3 us vs single-domain R5).
// global_load_lds offset MUST be 0 (R10 lesson: the immediate applies to the LDS
// address, not the global address).
__global__ __launch_bounds__(256, 2)
void attn_fwd(const float* __restrict__ q, const short* __restrict__ kb,
              const short* __restrict__ vtb, float* __restrict__ out)
{
    // XCD swizzle (T1, verified): 512 blocks, (lin&7)=XCD, 2 heads per XCD ->
    // 2 MB K/V working set <= 4 MB L2. Bijective: 512 % 8 == 0.
    const int lin   = blockIdx.x;
    const int idx   = lin >> 3;              // 0..63 within this XCD
    const int h     = (lin & 7) * 2 + (idx >> 5);
    const int qbase = (idx & 31) * BM;

    const int tid   = threadIdx.x;
    const int wave  = tid >> 6;              // 0..3
    const int kg    = wave >> 1;             // key-half: 0 -> tiles 0..31, 1 -> 32..63
    const int qg    = wave & 1;              // q-group / stager index within half
    const int lane  = tid & 63;
    const int lm    = lane & 15;
    const int quad  = lane >> 4;
    const int sw    = lm & 7;
    const int T0    = kg * NTH;              // tile offset of this key-half

    // per-key-half ring-2 buffers: 2 x (2x8KB K + 2x8KB V) = 64 KB -> 2 blocks/CU
    __shared__ short Kt[2][2][BN * D];   // [kg][slot][key*64+d], 16B-chunk XOR-swizzled
    __shared__ short Vt[2][2][BN * D];   // [kg][slot][d*64+key'], sigma-permuted, XOR-swizzled

    const float c1 = 0.18033688011112042f;   // 0.125 * log2(e), folded into Q

    // Q fragments (B-operand of S^T mfma): B[n=lm][k = kc*32 + quad*8 + j], pre-scaled
    bf16x8 bq[4][2];
    #pragma unroll
    for (int g = 0; g < 4; ++g) {
        const int qrow = qbase + qg * 64 + g * 16 + lm;
        #pragma unroll
        for (int kc = 0; kc < 2; ++kc) {
            const float* qp = q + ((size_t)qrow * H + h) * D + kc * 32 + quad * 8;
            f4v q0 = *(const f4v*)qp;
            f4v q1 = *(const f4v*)(qp + 4);
            BF8 b;
            b.u[0] = pk2(q0[0] * c1, q0[1] * c1); b.u[1] = pk2(q0[2] * c1, q0[3] * c1);
            b.u[2] = pk2(q1[0] * c1, q1[1] * c1); b.u[3] = pk2(q1[2] * c1, q1[3] * c1);
            bq[g][kc] = b.v;
        }
    }

    // all-ones A fragment for the l-accumulating MFMA (bf16 1.0 = 0x3F80)
    BF8 ones;
    ones.u[0] = ones.u[1] = ones.u[2] = ones.u[3] = 0x3F803F80u;

    const f32x4 fz = (f32x4){0.f, 0.f, 0.f, 0.f};
    f32x4 o[4][4];   // O^T accum: lane holds d=mb*16+quad*4+r, q=g*16+lm
    #pragma unroll
    for (int g = 0; g < 4; ++g)
        #pragma unroll
        for (int mb = 0; mb < 4; ++mb) o[g][mb] = fz;
    f32x4 lacc[4];   // l accum via ones-MFMA: each lane's [r] = full partial l
    lacc[0] = fz; lacc[1] = fz; lacc[2] = fz; lacc[3] = fz;

    // staging (R5's proven per-set recipe, 4 sets per wave): buffer = 512 x 16B
    // chunks; chunk ci -> row ci>>3, pos ci&7, source col chunk = pos ^ (row&7).
    // This wave's sets: ci_j = qg*256 + j*64 + lane, j = 0..3.
    const int ci0 = qg * 256 + 0 * 64 + lane;
    const int ci1 = qg * 256 + 1 * 64 + lane;
    const int ci2 = qg * 256 + 2 * 64 + lane;
    const int ci3 = qg * 256 + 3 * 64 + lane;
    const int kr0 = ci0 >> 3, kp0 = (ci0 & 7) ^ (kr0 & 7);
    const int kr1 = ci1 >> 3, kp1 = (ci1 & 7) ^ (kr1 & 7);
    const int kr2 = ci2 >> 3, kp2 = (ci2 & 7) ^ (kr2 & 7);
    const int kr3 = ci3 >> 3, kp3 = (ci3 & 7) ^ (kr3 & 7);

    const short* kh = kb  + (size_t)h * NSEQ * D;
    const short* vh = vtb + (size_t)h * D * NSEQ;
    const short* pk0 = kh + (size_t)(T0 * BN + kr0) * D + kp0 * 8;
    const short* pk1 = kh + (size_t)(T0 * BN + kr1) * D + kp1 * 8;
    const short* pk2_ = kh + (size_t)(T0 * BN + kr2) * D + kp2 * 8;
    const short* pk3 = kh + (size_t)(T0 * BN + kr3) * D + kp3 * 8;
    const short* pv0 = vh + (size_t)kr0 * NSEQ + T0 * BN + kp0 * 8;
    const short* pv1 = vh + (size_t)kr1 * NSEQ + T0 * BN + kp1 * 8;
    const short* pv2 = vh + (size_t)kr2 * NSEQ + T0 * BN + kp2 * 8;
    const short* pv3 = vh + (size_t)kr3 * NSEQ + T0 * BN + kp3 * 8;

    auto issue = [&](int b) {
        short* kd = &Kt[kg][b][qg * 2048];      // set j dest: chunk qg*256 + j*64
        short* vd = &Vt[kg][b][qg * 2048];
        __builtin_amdgcn_global_load_lds(TO_GBL(pk0), TO_LDS(kd +    0), 16, 0, 0);
        __builtin_amdgcn_global_load_lds(TO_GBL(pk1), TO_LDS(kd +  512), 16, 0, 0);
        __builtin_amdgcn_global_load_lds(TO_GBL(pk2_), TO_LDS(kd + 1024), 16, 0, 0);
        __builtin_amdgcn_global_load_lds(TO_GBL(pk3), TO_LDS(kd + 1536), 16, 0, 0);
        __builtin_amdgcn_global_load_lds(TO_GBL(pv0), TO_LDS(vd +    0), 16, 0, 0);
        __builtin_amdgcn_global_load_lds(TO_GBL(pv1), TO_LDS(vd +  512), 16, 0, 0);
        __builtin_amdgcn_global_load_lds(TO_GBL(pv2), TO_LDS(vd + 1024), 16, 0, 0);
        __builtin_amdgcn_global_load_lds(TO_GBL(pv3), TO_LDS(vd + 1536), 16, 0, 0);
        pk0 += BN * D; pk1 += BN * D; pk2_ += BN * D; pk3 += BN * D;
        pv0 += BN; pv1 += BN; pv2 += BN; pv3 += BN;
    };

    const int posK0 = ((0 + quad) ^ sw) * 8;
    const int posK1 = ((4 + quad) ^ sw) * 8;

    // R5's verified compute body (64 q/wave, K-frag reuse across 4 g's)
    auto compute = [&](int b) {
        const short* K_ = Kt[kg][b];
        const short* V_ = Vt[kg][b];

        bf16x8 kf0[4], kf1[4];
        #pragma unroll
        for (int nb = 0; nb < 4; ++nb) {
            kf0[nb] = *(const bf16x8*)&K_[(nb * 16 + lm) * 64 + posK0];
            kf1[nb] = *(const bf16x8*)&K_[(nb * 16 + lm) * 64 + posK1];
        }

        BF8 pb[4][2];
        #pragma unroll
        for (int g = 0; g < 4; ++g) {
            f32x4 st[4];
            #pragma unroll
            for (int nb = 0; nb < 4; ++nb) {
                st[nb] = __builtin_amdgcn_mfma_f32_16x16x32_bf16(kf0[nb], bq[g][0], fz, 0, 0, 0);
                st[nb] = __builtin_amdgcn_mfma_f32_16x16x32_bf16(kf1[nb], bq[g][1], st[nb], 0, 0, 0);
            }
            #pragma unroll
            for (int nb = 0; nb < 4; ++nb)
                #pragma unroll
                for (int r = 0; r < 4; ++r)
                    st[nb][r] = fexp2(st[nb][r]);
            #pragma unroll
            for (int c = 0; c < 2; ++c) {
                pb[g][c].u[0] = pk2(st[2 * c][0],     st[2 * c][1]);
                pb[g][c].u[1] = pk2(st[2 * c][2],     st[2 * c][3]);
                pb[g][c].u[2] = pk2(st[2 * c + 1][0], st[2 * c + 1][1]);
                pb[g][c].u[3] = pk2(st[2 * c + 1][2], st[2 * c + 1][3]);
            }
        }

        #pragma unroll
        for (int c = 0; c < 2; ++c)
            #pragma unroll
            for (int g = 0; g < 4; ++g)
                lacc[g] = __builtin_amdgcn_mfma_f32_16x16x32_bf16(ones.v, pb[g][c].v, lacc[g], 0, 0, 0);

        #pragma unroll
        for (int c = 0; c < 2; ++c) {
            const int pos = ((c * 4 + quad) ^ sw) * 8;
            #pragma unroll
            for (int mb = 0; mb < 4; ++mb) {
                bf16x8 vf = *(const bf16x8*)&V_[(mb * 16 + lm) * 64 + pos];
                #pragma unroll
                for (int g = 0; g < 4; ++g)
                    o[g][mb] = __builtin_amdgcn_mfma_f32_16x16x32_bf16(vf, pb[g][c].v, o[g][mb], 0, 0, 0);
            }
        }
    };

    // ---- ring-2 schedule: one barrier + one vmcnt(0) per tile, 32 tiles per kg ----
#define WAITV0 asm volatile("s_waitcnt vmcnt(0)" ::: "memory")
#define BARRIER() do { __builtin_amdgcn_s_barrier(); asm volatile("" ::: "memory"); } while (0)

    issue(0);
    for (int t = 0; t < NTH - 1; ++t) {
        WAITV0; BARRIER();
        issue((t + 1) & 1);
        compute(t & 1);
    }
    WAITV0; BARRIER();
    compute((NTH - 1) & 1);

    // ---- split-K merge + epilogue ----
    float* Mo = (float*)&Kt[0][0][0];   // 128 slots x 64 words (o partials)    = 32 KB
    float* Ml = (float*)&Vt[0][0][0];   // 128 slots x 4  words (lacc partials) =  2 KB
    const int slot = qg * 64 + lane;

    __syncthreads();   // all computes done before overwriting ring buffers
    if (kg == 1) {
        float* p = Mo + slot * 64;
        #pragma unroll
        for (int g = 0; g < 4; ++g)
            #pragma unroll
            for (int mb = 0; mb < 4; ++mb) {
                const int fi = g * 4 + mb;
                *(f32x4*)(p + ((fi ^ (slot & 15)) * 4)) = o[g][mb];
            }
        f32x4 lv = (f32x4){lacc[0][0], lacc[1][0], lacc[2][0], lacc[3][0]};
        *(f32x4*)(Ml + slot * 4) = lv;
    }
    __syncthreads();   // kg1's partials visible
    if (kg == 0) {
        const float* p = Mo + slot * 64;
        const f32x4 lv = *(const f32x4*)(Ml + slot * 4);
        #pragma unroll
        for (int g = 0; g < 4; ++g) {
            const float inv = 1.0f / (lacc[g][0] + lv[g]);
            const int qrow = qbase + qg * 64 + g * 16 + lm;
            float* op = out + ((size_t)qrow * H + h) * D + quad * 4;
            #pragma unroll
            for (int mb = 0; mb < 4; ++mb) {
                const int fi = g * 4 + mb;
                const f32x4 ob = *(const f32x4*)(p + ((fi ^ (slot & 15)) * 4));
                f4v w;
                #pragma unroll
                for (int r = 0; r < 4; ++r) w[r] = (o[g][mb][r] + ob[r]) * inv;
                *(f4v*)(op + mb * 16) = w;
            }
        }
    }
}

extern "C" void kernel_launch(void* const* d_in, const int* in_sizes, int n_in,
                              void* d_out, int out_size, void* d_ws, size_t ws_size,
                              hipStream_t stream) {
    const float* q = (const float*)d_in[0];
    const float* k = (const float*)d_in[1];
    const float* v = (const float*)d_in[2];
    float* out = (float*)d_out;

    short* kb = (short*)d_ws;                        // 8 MB bf16 K [h][n][d]
    short* vt = kb + (size_t)H * NSEQ * D;           // 8 MB bf16 V^T [h][d][n'] (sigma-permuted)

    prep<<<dim3(NSEQ / 128, H), dim3(256), 0, stream>>>(k, v, kb, vt);
    attn_fwd<<<dim3((NSEQ / BM) * H), dim3(256), 0, stream>>>(q, kb, vt, out);
}